// Round 4
// baseline (128.216 us; speedup 1.0000x reference)
//
#include <hip/hip_runtime.h>

#define NN 2048

typedef unsigned short u16;
typedef __attribute__((ext_vector_type(8))) short short8;
typedef __attribute__((ext_vector_type(4))) float floatx4;

__device__ __forceinline__ u16 f2bf(float f) {
  unsigned u = __float_as_uint(f);
  u += 0x7FFF + ((u >> 16) & 1);   // RNE
  return (u16)(u >> 16);
}

__device__ __forceinline__ float bf2f(u16 h) {
  return __uint_as_float(((unsigned)h) << 16);
}

// async global->LDS, 16B per lane. LDS dest = wave-uniform base + lane*16.
__device__ __forceinline__ void load_lds16(const u16* g, u16* l) {
  __builtin_amdgcn_global_load_lds(
      (const __attribute__((address_space(1))) unsigned int*)g,
      (__attribute__((address_space(3))) unsigned int*)l,
      16, 0, 0);
}

// ---------------------------------------------------------------------------
// prep v2: fp32 -> bf16 (Abf row-major + AbfT transposed), fp32 row-sum
// partials degp[mat][row][32], zero tri. Transpose via swizzled LDS:
//   element (r,c) of the 64x64 tile stored at
//   c*72 + (( (r>>4) ^ ((c>>2)&3) ^ ((c>>4)&3) )*16) + (r&15)
// scatter-writes are scalar u16 (~4-way worst); gather-reads are ds_read_b128
// (2-way, free); global output stores are 16 B coalesced.
// grid (32,32,2), block 256.
// ---------------------------------------------------------------------------
__global__ __launch_bounds__(256) void prep_kernel(
    const float* __restrict__ A1, const float* __restrict__ A2,
    u16* __restrict__ Abf, u16* __restrict__ AbfT,
    float* __restrict__ degp, float* __restrict__ tri) {
  __shared__ u16 Tl[64 * 72];
  const int bx = blockIdx.x, by = blockIdx.y, bz = blockIdx.z;
  const float* __restrict__ A = bz ? A2 : A1;
  u16* __restrict__ ab = Abf + (size_t)bz * (NN * (size_t)NN);
  u16* __restrict__ at = AbfT + (size_t)bz * (NN * (size_t)NN);
  float* __restrict__ dp = degp + (size_t)bz * (32 * NN);
  const int t = threadIdx.x;
  const int r0 = by * 64, c0 = bx * 64;
  const int rs = t >> 4, cs = t & 15;
  const int cswz = (cs & 3) ^ (cs >> 2);   // ((c>>2)&3) ^ ((c>>4)&3) for c=cs*4+i

  if (bx == 0 && t < 64) tri[bz * NN + by * 64 + t] = 0.f;

#pragma unroll
  for (int it = 0; it < 4; ++it) {
    const int r = it * 16 + rs;
    const float4 fv = *(const float4*)(A + (size_t)(r0 + r) * NN + c0 + cs * 4);
    ushort4 b;
    b.x = f2bf(fv.x); b.y = f2bf(fv.y); b.z = f2bf(fv.z); b.w = f2bf(fv.w);
    *(ushort4*)(ab + (size_t)(r0 + r) * NN + c0 + cs * 4) = b;
    const int chk = (it ^ cswz) * 16 + rs;
    Tl[(cs * 4 + 0) * 72 + chk] = b.x;
    Tl[(cs * 4 + 1) * 72 + chk] = b.y;
    Tl[(cs * 4 + 2) * 72 + chk] = b.z;
    Tl[(cs * 4 + 3) * 72 + chk] = b.w;
    // exact fp32 row-sum partial over this 64-col slab
    float s = fv.x + fv.y + fv.z + fv.w;
    s += __shfl_xor(s, 1); s += __shfl_xor(s, 2);
    s += __shfl_xor(s, 4); s += __shfl_xor(s, 8);
    if (cs == 0) dp[(r0 + r) * 32 + bx] = s;
  }
  __syncthreads();
  // gather: thread covers output row c' (col of tile), 8 consecutive r
#pragma unroll
  for (int p = 0; p < 2; ++p) {
    const int cp = p * 32 + (t >> 3);        // 0..63
    const int k8 = t & 7;                    // r-chunk of 8
    const int chunk = k8 >> 1, half = k8 & 1;
    const int sw = chunk ^ ((cp >> 2) & 3) ^ ((cp >> 4) & 3);
    const short8 v = *(const short8*)(Tl + cp * 72 + sw * 16 + half * 8);
    *(short8*)(at + (size_t)(c0 + cp) * NN + r0 + k8 * 8) = v;
  }
}

#define MFMA_BODY(PB)                                                     \
  {                                                                       \
    short8 af[4], bfr[4];                                                 \
    _Pragma("unroll")                                                     \
    for (int tm = 0; tm < 4; ++tm)                                        \
      af[tm] = *(const short8*)(smem + (PB) + aoff[tm]);                  \
    _Pragma("unroll")                                                     \
    for (int tn = 0; tn < 4; ++tn)                                        \
      bfr[tn] = *(const short8*)(smem + (PB) + boff[tn]);                 \
    _Pragma("unroll")                                                     \
    for (int tm = 0; tm < 4; ++tm)                                        \
      _Pragma("unroll")                                                   \
      for (int tn = 0; tn < 4; ++tn)                                      \
        acc[tm][tn] = __builtin_amdgcn_mfma_f32_16x16x32_bf16(            \
            af[tm], bfr[tn], acc[tm][tn], 0, 0, 0);                       \
  }

#define PREFETCH(KK, DB)                                                  \
  load_lds16(gA0 + (KK), smem + (DB) + sA0);                              \
  load_lds16(gA1 + (KK), smem + (DB) + sA1);                              \
  load_lds16(gB0 + (KK), smem + (DB) + sB0);                              \
  load_lds16(gB1 + (KK), smem + (DB) + sB1);

#define FENCE asm volatile("" ::: "memory")

// ---------------------------------------------------------------------------
// gemm_tri: tri[i] += sum_j (A@A)_{ij} * A_{ji}, fused; never materializes A@A.
// Split-K=2 (z = mat*2 + kz, K-half [kz*1024,+1024)) — works ONLY because the
// kernel now fits the <=128-reg class (VGPR 60 + AGPR 64): 4 waves/SIMD ->
// 4 blocks/CU co-resident (R1/R2 at 152 regs were capped at 2 blocks/CU,
// which is why R2's split-K ran as two sequential rounds and regressed).
// Software-pipelined double-buffered LDS, raw s_barrier + vmcnt(4).
// grid (16,16,4), block 256, LDS 34816 (4x = 139 KB <= 160 KB).
// ---------------------------------------------------------------------------
__global__ __launch_bounds__(256, 4) void gemm_tri_kernel(
    const u16* __restrict__ Abf, const u16* __restrict__ AbfT,
    float* __restrict__ tri) {
  // loop: buf0 [0,8192) u16, buf1 [8192,16384); each buf: As 4096 + Bs 4096.
  // epilogue reuses [0,17408) as T 128x136.
  __shared__ u16 smem[17408];

  const int tid = threadIdx.x;
  const int w = tid >> 6, lane = tid & 63;
  const int wm = w >> 1, wn = w & 1;
  const int cl = lane & 15, g = lane >> 4;
  const int i0 = blockIdx.y * 128, j0 = blockIdx.x * 128;
  const int mz = blockIdx.z >> 1, kz = blockIdx.z & 1;
  const size_t mat = (size_t)mz * (NN * (size_t)NN);
  const u16* __restrict__ Am = Abf + mat;
  const u16* __restrict__ ATm = AbfT + mat;
  float* __restrict__ triM = tri + mz * NN;

  // staging: wave w stages 2 slices for As, 2 for Bs per K-step.
  // LDS slot s (16B) -> row = s>>2, stored-chunk c' = s&3 holds global chunk
  // c = c' ^ ((row>>1)&3)  (global-side XOR swizzle -> frag reads conflict-free)
  const int s0 = (w * 2 + 0) * 64 + lane;
  const int s1 = (w * 2 + 1) * 64 + lane;
  const int r0s = s0 >> 2, c0s = (s0 & 3) ^ ((r0s >> 1) & 3);
  const int r1s = s1 >> 2, c1s = (s1 & 3) ^ ((r1s >> 1) & 3);
  const int kbase = kz * 1024;
  const u16* gA0 = Am + (size_t)(i0 + r0s) * NN + kbase + c0s * 8;
  const u16* gA1 = Am + (size_t)(i0 + r1s) * NN + kbase + c1s * 8;
  const u16* gB0 = ATm + (size_t)(j0 + r0s) * NN + kbase + c0s * 8;
  const u16* gB1 = ATm + (size_t)(j0 + r1s) * NN + kbase + c1s * 8;
  const int sA0 = (w * 2 + 0) * 512, sA1 = (w * 2 + 1) * 512;
  const int sB0 = 4096 + sA0, sB1 = 4096 + sA1;

  // fragment read offsets (u16 elements) within a buffer
  const int swz = g ^ ((cl >> 1) & 3);
  int aoff[4], boff[4];
#pragma unroll
  for (int tm = 0; tm < 4; ++tm)
    aoff[tm] = (wm * 64 + tm * 16 + cl) * 32 + swz * 8;
#pragma unroll
  for (int tn = 0; tn < 4; ++tn)
    boff[tn] = 4096 + (wn * 64 + tn * 16 + cl) * 32 + swz * 8;

  floatx4 acc[4][4] = {};

  // preamble: iter 0 -> buf 0
  PREFETCH(0, 0)

  // 15 double-steps, iters 0..29 (all with prefetch)
#pragma unroll 1
  for (int d = 0; d < 15; ++d) {
    // iter 2d: compute buf0, prefetch (2d+1) -> buf1
    FENCE; __builtin_amdgcn_s_barrier(); FENCE;
    PREFETCH((2 * d + 1) * 32, 8192)
    __builtin_amdgcn_s_waitcnt(0x0F74);  // vmcnt(4)
    FENCE; __builtin_amdgcn_s_barrier(); FENCE;
    MFMA_BODY(0)
    // iter 2d+1: compute buf1, prefetch (2d+2) -> buf0
    FENCE; __builtin_amdgcn_s_barrier(); FENCE;
    PREFETCH((2 * d + 2) * 32, 0)
    __builtin_amdgcn_s_waitcnt(0x0F74);  // vmcnt(4)
    FENCE; __builtin_amdgcn_s_barrier(); FENCE;
    MFMA_BODY(8192)
  }
  // iter 30: compute buf0, prefetch 31 -> buf1
  FENCE; __builtin_amdgcn_s_barrier(); FENCE;
  PREFETCH(31 * 32, 8192)
  __builtin_amdgcn_s_waitcnt(0x0F74);
  FENCE; __builtin_amdgcn_s_barrier(); FENCE;
  MFMA_BODY(0)
  // iter 31: compute buf1, no prefetch
  FENCE; __builtin_amdgcn_s_barrier(); FENCE;
  __builtin_amdgcn_s_waitcnt(0x0F70);  // vmcnt(0)
  FENCE; __builtin_amdgcn_s_barrier(); FENCE;
  MFMA_BODY(8192)

  // epilogue: tri[i0+r] += sum_c C[r][c] * A^T[i0+r][j0+c]
  __syncthreads();
#pragma unroll
  for (int it = 0; it < 8; ++it) {
    const int idx = tid + it * 256;
    const int r = idx >> 4, co = (idx & 15) * 8;
    *(uint4*)(smem + r * 136 + co) =
        *(const uint4*)(ATm + (size_t)(i0 + r) * NN + j0 + co);
  }
  __syncthreads();

#pragma unroll
  for (int tm = 0; tm < 4; ++tm) {
#pragma unroll
    for (int reg = 0; reg < 4; ++reg) {
      const int rloc = wm * 64 + tm * 16 + g * 4 + reg;  // C/D: row=(lane>>4)*4+reg
      float v = 0.f;
#pragma unroll
      for (int tn = 0; tn < 4; ++tn) {
        const int cloc = wn * 64 + tn * 16 + cl;          // C/D: col=lane&15
        v += acc[tm][tn][reg] * bf2f(smem[rloc * 136 + cloc]);
      }
      v += __shfl_xor(v, 1);
      v += __shfl_xor(v, 2);
      v += __shfl_xor(v, 4);
      v += __shfl_xor(v, 8);
      if (cl == 0) atomicAdd(&triM[i0 + rloc], v);
    }
  }
}

// ---------------------------------------------------------------------------
// finalize stage 1: grid 16 x 1024 threads; block b reduces rows [b*128,+128).
// ---------------------------------------------------------------------------
__global__ __launch_bounds__(1024) void finalize1_kernel(
    const float* __restrict__ degp, const float* __restrict__ tri,
    float* __restrict__ part) {
  __shared__ float red[32];
  const int t = threadIdx.x;
  const int r = blockIdx.x * 128 + (t >> 3);   // row
  const int q = (t & 7) * 4;                   // degp chunk
  const float4 v1 = *(const float4*)(degp + (size_t)r * 32 + q);
  const float4 v2 = *(const float4*)(degp + 32 * NN + (size_t)r * 32 + q);
  float d1 = v1.x + v1.y + v1.z + v1.w;
  float d2 = v2.x + v2.y + v2.z + v2.w;
#pragma unroll
  for (int m = 1; m < 8; m <<= 1) {
    d1 += __shfl_xor(d1, m);
    d2 += __shfl_xor(d2, m);
  }
  float sdd = 0.f, scc = 0.f;
  if ((t & 7) == 0) {
    const float t1 = tri[r], t2 = tri[NN + r];
    const float e1 = d1 < 2.f ? 1.f : d1;
    const float e2 = d2 < 2.f ? 1.f : d2;
    sdd = fabsf(d1 - d2);
    scc = fabsf(t1 / (e1 * (e1 - 1.f)) - t2 / (e2 * (e2 - 1.f)));
  }
#pragma unroll
  for (int m = 8; m < 64; m <<= 1) {
    sdd += __shfl_xor(sdd, m);
    scc += __shfl_xor(scc, m);
  }
  const int wv = t >> 6, ln = t & 63;
  if (ln == 0) { red[wv] = sdd; red[16 + wv] = scc; }
  __syncthreads();
  if (t == 0) {
    float a = 0.f, b = 0.f;
#pragma unroll
    for (int i = 0; i < 16; ++i) { a += red[i]; b += red[16 + i]; }
    part[blockIdx.x * 2 + 0] = a;
    part[blockIdx.x * 2 + 1] = b;
  }
}

__global__ void finalize2_kernel(const float* __restrict__ part,
                                 float* __restrict__ out) {
  if (threadIdx.x == 0) {
    float a = 0.f, b = 0.f;
#pragma unroll
    for (int i = 0; i < 16; ++i) { a += part[i * 2]; b += part[i * 2 + 1]; }
    const float ds = expf(-a * (1.f / (float)NN));
    const float cs = expf(-b * (1.f / (float)NN));
    out[0] = ds;
    out[1] = cs;
    out[2] = 0.5f * (ds + cs);
  }
}

extern "C" void kernel_launch(void* const* d_in, const int* in_sizes, int n_in,
                              void* d_out, int out_size, void* d_ws, size_t ws_size,
                              hipStream_t stream) {
  (void)in_sizes; (void)n_in; (void)out_size; (void)ws_size;
  const float* A1 = (const float*)d_in[0];
  const float* A2 = (const float*)d_in[1];
  float* out = (float*)d_out;

  // workspace layout:
  //   Abf  [2][2048*2048] u16
  //   AbfT [2][2048*2048] u16
  //   tri  [2][2048] f32
  //   degp [2][2048][32] f32
  //   part [32] f32
  u16* Abf = (u16*)d_ws;
  u16* AbfT = Abf + 2 * (size_t)NN * NN;
  float* tri = (float*)(AbfT + 2 * (size_t)NN * NN);
  float* degp = tri + 2 * NN;
  float* part = degp + 2 * 32 * NN;

  prep_kernel<<<dim3(32, 32, 2), 256, 0, stream>>>(A1, A2, Abf, AbfT, degp, tri);
  gemm_tri_kernel<<<dim3(16, 16, 4), 256, 0, stream>>>(Abf, AbfT, tri);
  finalize1_kernel<<<16, 1024, 0, stream>>>(degp, tri, part);
  finalize2_kernel<<<1, 64, 0, stream>>>(part, out);
}